// Round 8
// baseline (4943.056 us; speedup 1.0000x reference)
//
#include <hip/hip_runtime.h>
#include <stdint.h>

#define V 4096
#define D 128
#define E 12288
#define NPAD 16384
#define HALF 8192
#define TARGET 2048
#define MAXM (V - TARGET)    // 2048 max merges
#define ROWU32 256           // 4096 fields * 2 bits = 256 u32 per row (1 KB)
#define CAP 32               // candidates considered per round

// s_waitcnt imms (gfx9): bits 3:0 vmcnt lo, 6:4 expcnt, 11:8 lgkmcnt, 15:14 vmcnt hi
#define WAIT_VM0   0x0F70    // vmcnt(0) only

// ws layout (bytes)
#define WS_N      0u                            // V*ROWU32*4 = 4 MB (2-bit matrix)
#define WS_PRI    (V * ROWU32 * 4u)             // V float
#define WS_KEYS   (WS_PRI + V * 4u)             // NPAD u64
#define WS_PK     (WS_KEYS + NPAD * 8u)         // E u32 (sorted packed edges)
#define WS_PAIRS  (WS_PK + E * 4u)              // MAXM u32
#define WS_MCOUNT (WS_PAIRS + MAXM * 4u)        // 1 int
#define WS_ALIVE  (WS_MCOUNT + 16u)             // V u8

typedef const __attribute__((address_space(1))) unsigned* gas1_t;
typedef __attribute__((address_space(3))) unsigned* las3_t;

__device__ __forceinline__ unsigned getf(const uint4& r, int c) {
    unsigned lo = (c & 2) ? r.z : r.x;
    unsigned hi = (c & 2) ? r.w : r.y;
    return (c & 1) ? hi : lo;
}
__device__ __forceinline__ void andf(uint4& r, int c, unsigned msk) {
    if (c == 0) r.x &= msk; else if (c == 1) r.y &= msk;
    else if (c == 2) r.z &= msk; else r.w &= msk;
}
// elementwise saturating add over 16x2-bit fields (values {0,2,3}; assoc+comm)
__device__ __forceinline__ uint4 satq(uint4 a, uint4 b) {
    uint4 r;
    r.x = a.x | b.x | ((a.x & b.x & 0xAAAAAAAAu) >> 1);
    r.y = a.y | b.y | ((a.y & b.y & 0xAAAAAAAAu) >> 1);
    r.z = a.z | b.z | ((a.z & b.z & 0xAAAAAAAAu) >> 1);
    r.w = a.w | b.w | ((a.w & b.w & 0xAAAAAAAAu) >> 1);
    return r;
}

__global__ void k_scatter(const int* __restrict__ edges, unsigned* __restrict__ n32) {
    int e = blockIdx.x * 256 + threadIdx.x;
    if (e < E) {
        int a = edges[e], b = edges[E + e];
        atomicOr(&n32[a * ROWU32 + (b >> 4)], 2u << ((b & 15) * 2));
        atomicOr(&n32[b * ROWU32 + (a >> 4)], 2u << ((a & 15) * 2));
    }
}

// numpy pairwise f32 sum for n=128 (matches np oracle reduction order)
__global__ void k_pri(const float* __restrict__ f, float* __restrict__ pri) {
    int v = blockIdx.x * 256 + threadIdx.x;
    if (v < V) {
        const float* p = f + v * D;
        float r[8];
#pragma unroll
        for (int j = 0; j < 8; j++) r[j] = __fmul_rn(p[j], p[j]);
        for (int i = 8; i < D; i += 8) {
#pragma unroll
            for (int j = 0; j < 8; j++)
                r[j] = __fadd_rn(r[j], __fmul_rn(p[i + j], p[i + j]));
        }
        float s01 = __fadd_rn(r[0], r[1]);
        float s23 = __fadd_rn(r[2], r[3]);
        float s45 = __fadd_rn(r[4], r[5]);
        float s67 = __fadd_rn(r[6], r[7]);
        pri[v] = __fadd_rn(__fadd_rn(s01, s23), __fadd_rn(s45, s67));
    }
}

__global__ void k_keys(const int* __restrict__ edges, const float* __restrict__ pri,
                       unsigned long long* __restrict__ keys) {
    int s = blockIdx.x * 256 + threadIdx.x;
    if (s < NPAD) {
        unsigned long long rec;
        if (s < E) {
            int a = edges[s], b = edges[E + s];
            float k = __fadd_rn(pri[a], pri[b]);   // epri >= 0 -> bits monotone
            rec = ((unsigned long long)__float_as_uint(k) << 32) | (unsigned)s;
        } else {
            rec = (0xFFFFFFFFull << 32) | (unsigned)s;
        }
        keys[s] = rec;
    }
}

// bitonic sort one 8192-element half in LDS; 2 blocks run concurrently
__launch_bounds__(1024)
__global__ void k_sort2(unsigned long long* __restrict__ keys) {
    __shared__ unsigned long long srt[HALF];
    const int tid = threadIdx.x;
    unsigned long long* base = keys + blockIdx.x * HALF;
    for (int s = tid; s < HALF; s += 1024) srt[s] = base[s];
    __syncthreads();
    for (int k = 2; k <= HALF; k <<= 1) {
        for (int j = k >> 1; j >= 1; j >>= 1) {
            for (int i = tid; i < HALF; i += 1024) {
                int ixj = i ^ j;
                if (ixj > i) {
                    unsigned long long x = srt[i], y = srt[ixj];
                    bool up = ((i & k) == 0);
                    if ((x > y) == up) { srt[i] = y; srt[ixj] = x; }
                }
            }
            __syncthreads();
        }
    }
    for (int s = tid; s < HALF; s += 1024) base[s] = srt[s];
}

// merge-path the two sorted halves; emit packed (v0<<16|v1) in global order
__launch_bounds__(64)
__global__ void k_mergepath(const unsigned long long* __restrict__ keys,
                            const int* __restrict__ edges, unsigned* __restrict__ pkG) {
    int t = blockIdx.x * 64 + threadIdx.x;
    if (t >= E / 64) return;
    const unsigned long long* A = keys;
    const unsigned long long* B = keys + HALF;
    int d = t * 64;
    int lo = d > HALF ? d - HALF : 0;
    int hi = d < HALF ? d : HALF;
    while (lo < hi) {
        int mid = (lo + hi) >> 1;
        if (A[mid] < B[d - 1 - mid]) lo = mid + 1; else hi = mid;
    }
    int ia = lo, ib = d - lo;
    for (int o = d; o < d + 64; o++) {
        bool takeA = (ib >= HALF) || (ia < HALF && A[ia] < B[ib]);
        unsigned long long r = takeA ? A[ia++] : B[ib++];
        int e = (int)(r & 0xFFFFFFFFull);
        int a = edges[e], b = edges[E + e];
        pkG[o] = ((unsigned)a << 16) | (unsigned)b;
    }
}

// ONE wave: R3 candidate-pool + EXACT SURVIVOR-CHAIN resolution.
// Same-survivor pairs (v0j==v0k=c): j's accept changes k's field to
// sat(2 + n[v1j][v1k]) -- so k's in-round decision is binary on one fetched
// field (dnz bit): dnz==0 -> still acceptable; dnz!=0 -> field=3, dead-final.
// Chains resolve fully in-round. Apply accumulates per survivor:
// row_c_final = sat(fetched_c + sum of member rows) (members pairwise dnz==0
// guarantees their rows carry 0 at each other's dying columns -> exact), then
// ONE orig^final diff pass emits all column fixups. Cross-star pairs keep
// R3's H1/H2 exact-conservative checks (also guarantees kept rows are never
// another group's fixup target -> no write races). Chain followers of a
// DEFERRED j defer (oracle order); of a kept j decide in-round.
__launch_bounds__(64, 1)
__global__ void k_collapse(const unsigned* __restrict__ pkG, unsigned* n32,
                           unsigned* __restrict__ pairsG, int* __restrict__ mcountG,
                           uint8_t* __restrict__ aliveG, float* __restrict__ out) {
    __shared__ unsigned shRows[2 * CAP * ROWU32];   // 64 KB: rank k -> slots 2k,2k+1
    __shared__ uint8_t  alive[V];                   // 4 KB
    __shared__ unsigned shCand[CAP];
    __shared__ unsigned shConf[CAP];                // cross conflict mask (bits j<k)
    __shared__ unsigned shDeadM[CAP];               // "j's v1 kills k" mask
    __shared__ unsigned shChain[CAP];               // same-survivor mask (v0j==v0k)
    __shared__ unsigned shDnz[CAP];                 // chain pair field n[v1j][v1k]!=0
    const int lane = threadIdx.x;
    for (int v = lane; v < V; v += 64) alive[v] = 1;
    __syncthreads();

    int cnt = V, mcount = 0, head = 64;
    // ---- pool state (one candidate per lane; lane order == priority order) ----
    unsigned pkv = pkG[lane];
    unsigned fv = 0u;
    bool fknown = false;
    bool dec = false;                               // decided-or-inactive

    while (true) {
        const int a = (int)(pkv >> 16), b = (int)(pkv & 0xFFFFu);
        // 1. alive check (monotone: dec==true is final)
        if (!dec && !(alive[a] && alive[b])) dec = true;
        // 2. resolve unknown fields (one drain covers prior round's stores)
        bool unk = !dec && !fknown;
        bool drained = false;
        if (__ballot(unk)) {
            __builtin_amdgcn_s_waitcnt(WAIT_VM0);
            drained = true;
            if (unk) {
                unsigned wv = *(volatile unsigned*)(n32 + a * ROWU32 + (b >> 4));
                fv = (wv >> ((b & 15) * 2)) & 3u;
                fknown = true;
            }
        }
        if (!dec && fv != 2u) dec = true;            // monotone reject (final)
        unsigned long long mF = __ballot(!dec);

        if (mF) {
            int limit = cnt - TARGET; if (limit > CAP) limit = CAP;
            int flagged = (int)__popcll(mF);
            int nacc = flagged < limit ? flagged : limit;

            // ---- SELECT: first nacc flagged lanes (= highest priority) ----
            int myK = -1;
            if (!dec) {
                int rank = (int)__popcll(mF & ((1ull << lane) - 1ull));
                if (rank < limit) { myK = rank; shCand[rank] = pkv; }
            }
            if (lane < CAP) {
                shConf[lane] = 0u; shDeadM[lane] = 0u;
                shChain[lane] = 0u; shDnz[lane] = 0u;
            }
            __syncthreads();

            // ---- FETCH rows (fixed slots; drain prior stores if not yet) ----
            if (!drained) __builtin_amdgcn_s_waitcnt(WAIT_VM0);
            for (int k = 0; k < nacc; k++) {
                unsigned cp = shCand[k];
                int v0 = (int)(cp >> 16), v1 = (int)(cp & 0xFFFFu);
                __builtin_amdgcn_global_load_lds(
                    (gas1_t)(n32 + v0 * ROWU32 + lane * 4),
                    (las3_t)(shRows + (2 * k) * ROWU32), 16, 0, 0);
                __builtin_amdgcn_global_load_lds(
                    (gas1_t)(n32 + v1 * ROWU32 + lane * 4),
                    (las3_t)(shRows + (2 * k + 1) * ROWU32), 16, 0, 0);
            }
            __builtin_amdgcn_s_waitcnt(WAIT_VM0);
            __syncthreads();

            // ---- CLASSIFY pairs (j<k), 16 pairs per lane ----
            for (int pp = lane; pp < CAP * CAP; pp += 64) {
                int k = pp >> 5, j = pp & 31;
                if (j < k && k < nacc) {
                    unsigned cj = shCand[j], ck = shCand[k];
                    int v0j = (int)(cj >> 16), v1j = (int)(cj & 0xFFFFu);
                    int v0k = (int)(ck >> 16), v1k = (int)(ck & 0xFFFFu);
                    bool dkill = (v0k == v1j) || (v1k == v1j);
                    if (dkill) {
                        atomicOr(&shDeadM[k], 1u << j);
                        atomicOr(&shConf[k], 1u << j);
                    } else if (v0j == v0k) {
                        // class-2a: same survivor. EXACT via dnz bit.
                        atomicOr(&shChain[k], 1u << j);
                        const unsigned* rBj = shRows + (2 * j + 1) * ROWU32;
                        unsigned d = (rBj[v1k >> 4] >> ((v1k & 15) * 2)) & 3u;
                        if (d) atomicOr(&shDnz[k], 1u << j);
                    } else {
                        bool c = (v1k == v0j);       // k dies into j's survivor: defer
                        const unsigned* rBj = shRows + (2 * j + 1) * ROWU32;
                        const unsigned* rBk = shRows + (2 * k + 1) * ROWU32;
                        // H1: {v0k,v1k} adjacent to v1j
                        c |= ((rBj[v0k >> 4] >> ((v0k & 15) * 2)) & 3u) != 0u;
                        c |= ((rBj[v1k >> 4] >> ((v1k & 15) * 2)) & 3u) != 0u;
                        // H2: v0j adjacent to v1k
                        c |= ((rBk[v0j >> 4] >> ((v0j & 15) * 2)) & 3u) != 0u;
                        if (c) atomicOr(&shConf[k], 1u << j);
                    }
                }
            }
            __syncthreads();

            // ---- GREEDY (replicated VALU): exact chain rule + DEAD + conf ----
            unsigned kept = 0u, blocked = 0u, deadm = 0u;
            int m = 0;
#pragma unroll
            for (int k = 0; k < CAP; k++) {
                if (k >= nacc) continue;
                unsigned bit = 1u << k;
                unsigned dead = shDeadM[k], chain = shChain[k];
                unsigned dnz = shDnz[k], conf = shConf[k];
                if ((dead & kept) || (chain & kept & dnz)) { deadm |= bit; continue; }
                if ((conf & (kept | blocked)) || (chain & blocked)) {
                    blocked |= bit; continue;
                }
                kept |= bit; m++;                    // chain&kept&~dnz: field stays 2
            }
            if (myK >= 0 && (((kept | deadm) >> myK) & 1u)) dec = true;

            // ---- MARK: alive + merge log (priority order) ----
            if (lane < nacc && ((kept >> lane) & 1u)) {
                unsigned cp = shCand[lane];
                alive[(int)(cp & 0xFFFFu)] = 0;
                int r = __popc(kept & ((1u << lane) - 1u));
                pairsG[mcount + r] = cp;
            }
            mcount += m; cnt -= m;
            __syncthreads();
            if (cnt == TARGET) break;                // no future rounds: skip apply

            // ---- APPLY: per-survivor accumulation, 2 lanes per candidate ----
            {
                int g = lane >> 1, sub = lane & 1;
                if (g < nacc && ((kept >> g) & 1u)) {
                    unsigned cp = shCand[g];
                    const int v0 = (int)(cp >> 16);
                    // group = kept candidates with my survivor (includes me)
                    unsigned grpM = 0u;
                    {
                        unsigned km = kept;
                        while (km) {
                            int kk = __ffs(km) - 1; km &= km - 1u;
                            if ((int)(shCand[kk] >> 16) == v0) grpM |= 1u << kk;
                        }
                    }
                    bool leader = ((grpM & ((1u << g) - 1u)) == 0u);
                    if (leader) {
                        const int wi0 = v0 >> 4;
                        const unsigned sh0 = (unsigned)((v0 & 15) * 2);
                        for (int t = 0; t < 32; t++) {
                            int u = sub * 32 + ((t + lane) & 31);  // bank spread
                            uint4 orig = ((const uint4*)(shRows + (2*g) * ROWU32))[u];
                            uint4 q = orig;
                            unsigned mm = grpM;
                            while (mm) {             // add all members' dying rows
                                int kk = __ffs(mm) - 1; mm &= mm - 1u;
                                q = satq(q, ((const uint4*)
                                             (shRows + (2*kk+1) * ROWU32))[u]);
                            }
                            // zero survivor col + all dying cols in this u
                            if ((v0 >> 6) == u)
                                andf(q, (v0 >> 4) & 3, ~(3u << ((v0 & 15) * 2)));
                            mm = grpM;
                            while (mm) {
                                int kk = __ffs(mm) - 1; mm &= mm - 1u;
                                int v1k = (int)(shCand[kk] & 0xFFFFu);
                                if ((v1k >> 6) == u)
                                    andf(q, (v1k >> 4) & 3,
                                         ~(3u << ((v1k & 15) * 2)));
                            }
                            ((uint4*)(n32 + v0 * ROWU32))[u] = q;
                            // diff pass: one fixup per changed alive column
                            uint4 dq;
                            dq.x = orig.x ^ q.x; dq.y = orig.y ^ q.y;
                            dq.z = orig.z ^ q.z; dq.w = orig.w ^ q.w;
#pragma unroll
                            for (int c2 = 0; c2 < 4; c2++) {
                                unsigned dd = getf(dq, c2);
                                if (!dd) continue;
                                int xbase = (u << 6) + (c2 << 4);
                                while (dd) {
                                    int qq = (__ffs(dd) - 1) >> 1;
                                    unsigned dx = (dd >> (qq * 2)) & 3u;
                                    dd &= ~(3u << (qq * 2));
                                    int x = xbase + qq;
                                    if (x != v0 && alive[x])
                                        atomicXor(n32 + x * ROWU32 + wi0,
                                                  dx << sh0);
                                }
                            }
                        }
                    }
                }
            }
            __syncthreads();

            // ---- INVALIDATE fknown: field (a,b) changes only if an endpoint
            // equals a kept survivor v0j (row write or column-v0j fixup) ----
            if (!dec && fknown) {
                unsigned km = kept;
                while (km) {
                    int j = __ffs(km) - 1; km &= km - 1u;
                    int v0j = (int)(shCand[j] >> 16);
                    if (a == v0j || b == v0j) { fknown = false; break; }
                }
            }
            __syncthreads();
        } else {
            if (head >= E) break;                    // pool empty, stream exhausted
        }

        // ---- COMPACT undecided to low lanes (order-preserving) + REFILL ----
        {
            unsigned long long mU = __ballot(!dec);
            int nU = (int)__popcll(mU);
            // src = index of lane-th set bit of mU (6-step binary search)
            int p = 0;
#pragma unroll
            for (int step = 32; step; step >>= 1) {
                int cand = p + step;
                unsigned long long pref =
                    (cand >= 64) ? ~0ull : ((1ull << cand) - 1ull);
                if ((int)__popcll(mU & pref) <= lane) p = cand;
            }
            unsigned npkv = (unsigned)__shfl((int)pkv, p);
            unsigned nfv  = (unsigned)__shfl((int)fv, p);
            int      nfk  = __shfl((int)fknown, p);
            if (lane < nU) {
                pkv = npkv; fv = nfv; fknown = (nfk != 0); dec = false;
            } else {
                int idx = head + lane - nU;
                if (idx < E) { pkv = pkG[idx]; fknown = false; dec = false; }
                else dec = true;                     // inactive forever
            }
            head += 64 - nU;
        }
    }

    for (int v = lane; v < V; v += 64) {
        uint8_t ao = alive[v];
        aliveG[v] = ao;
        out[V * D + v] = ao ? 1.0f : 0.0f;
    }
    if (lane == 0) { mcountG[0] = mcount; out[V * D + V] = (float)cnt; }
}

// Replay merge forest: per-vertex (root, weight) then scatter-add w*f[v] into out[root].
__launch_bounds__(256)
__global__ void k_apply(const float* __restrict__ f, const unsigned* __restrict__ pairsG,
                        const int* __restrict__ mcountG, float* __restrict__ out) {
    __shared__ unsigned pl[MAXM];
    __shared__ int rootL[256];
    __shared__ float wL[256];
    const int tid = threadIdx.x;
    const int mc = mcountG[0];
    for (int j = tid; j < mc; j += 256) pl[j] = pairsG[j];
    __syncthreads();
    int cur = blockIdx.x * 256 + tid;
    float w = 1.0f;
    for (int j = 0; j < mc; j++) {
        unsigned p = pl[j];
        int v0 = (int)(p >> 16), v1 = (int)(p & 0xFFFFu);
        if (cur == v1) { cur = v0; w *= 0.5f; }
        else if (cur == v0) w *= 0.5f;
    }
    rootL[tid] = cur;
    wL[tid] = w;
    __syncthreads();
    const int sub = tid >> 7;
    const int d = tid & 127;
    for (int s = 0; s < 256; s += 2) {
        int idx = s + sub;
        int vv = blockIdx.x * 256 + idx;
        atomicAdd(&out[rootL[idx] * D + d], wL[idx] * f[vv * D + d]);
    }
}

extern "C" void kernel_launch(void* const* d_in, const int* in_sizes, int n_in,
                              void* d_out, int out_size, void* d_ws, size_t ws_size,
                              hipStream_t stream) {
    (void)in_sizes; (void)n_in; (void)out_size; (void)ws_size;
    const float* features = (const float*)d_in[0];
    const int* edges = (const int*)d_in[1];
    uint8_t* ws = (uint8_t*)d_ws;
    unsigned* n32 = (unsigned*)(ws + WS_N);
    float* pri = (float*)(ws + WS_PRI);
    unsigned long long* keys = (unsigned long long*)(ws + WS_KEYS);
    unsigned* pkG = (unsigned*)(ws + WS_PK);
    unsigned* pairsG = (unsigned*)(ws + WS_PAIRS);
    int* mcountG = (int*)(ws + WS_MCOUNT);
    uint8_t* aliveG = ws + WS_ALIVE;
    float* out = (float*)d_out;

    hipMemsetAsync(n32, 0, (size_t)V * ROWU32 * 4, stream);
    hipMemsetAsync(out, 0, (size_t)V * D * sizeof(float), stream);
    k_pri<<<(V + 255) / 256, 256, 0, stream>>>(features, pri);
    k_scatter<<<(E + 255) / 256, 256, 0, stream>>>(edges, n32);
    k_keys<<<(NPAD + 255) / 256, 256, 0, stream>>>(edges, pri, keys);
    k_sort2<<<2, 1024, 0, stream>>>(keys);
    k_mergepath<<<(E / 64 + 63) / 64, 64, 0, stream>>>(keys, edges, pkG);
    k_collapse<<<1, 64, 0, stream>>>(pkG, n32, pairsG, mcountG, aliveG, out);
    k_apply<<<V / 256, 256, 0, stream>>>(features, pairsG, mcountG, out);
}